// Round 3
// baseline (145.848 us; speedup 1.0000x reference)
//
#include <hip/hip_runtime.h>
#include <hip/hip_fp16.h>

#define N_NODES 50000
#define E_EDGES 800000
#define NTILES  (E_EDGES / 16)   // 50000 exact
#define TPW 4                    // tiles per wave (ILP for latency hiding)

typedef __attribute__((ext_vector_type(8))) short short8;
typedef __attribute__((ext_vector_type(4))) float floatx4;

// float -> bf16 bits, round-to-nearest-even (used in prep only)
__device__ __forceinline__ short f2bf(float x) {
    union { float f; unsigned u; } v; v.f = x;
    unsigned r = v.u + 0x7FFFu + ((v.u >> 16) & 1u);
    return (short)(r >> 16);
}

// pack bf16x2 (RTZ) from two floats via v_perm_b32: 1 VALU per pair
__device__ __forceinline__ unsigned pk_bf16(float lo, float hi) {
    union { float f; unsigned u; } a, b; a.f = lo; b.f = hi;
    return __builtin_amdgcn_perm(b.u, a.u, 0x07060302u);
}

// Kernel A: per-node LayerNorm+ReLU -> h; out = bias + h @ root; zero agg row
__global__ __launch_bounds__(256) void node_kernel(
    const float* __restrict__ x, const float* __restrict__ gamma,
    const float* __restrict__ beta, const float* __restrict__ root,
    const float* __restrict__ bias, float* __restrict__ h,
    float* __restrict__ out, __half* __restrict__ agg)
{
    int n = blockIdx.x * blockDim.x + threadIdx.x;
    if (n >= N_NODES) return;
    const float* xr = x + n * 16;
    float xv[16];
    #pragma unroll
    for (int i = 0; i < 4; ++i) ((floatx4*)xv)[i] = ((const floatx4*)xr)[i];
    float mu = 0.f;
    #pragma unroll
    for (int i = 0; i < 16; ++i) mu += xv[i];
    mu *= (1.f / 16.f);
    float var = 0.f;
    #pragma unroll
    for (int i = 0; i < 16; ++i) { float d = xv[i] - mu; var += d * d; }
    var *= (1.f / 16.f);
    float rs = rsqrtf(var + 1e-5f);
    float hv[16];
    #pragma unroll
    for (int i = 0; i < 16; ++i) {
        float t = (xv[i] - mu) * rs * gamma[i] + beta[i];
        hv[i] = t > 0.f ? t : 0.f;
    }
    float* hr = h + n * 16;
    #pragma unroll
    for (int i = 0; i < 4; ++i) ((floatx4*)hr)[i] = ((floatx4*)hv)[i];

    // zero the f16 aggregation row for this node (32 B) before edge_kernel runs
    floatx4 z = {0.f, 0.f, 0.f, 0.f};
    floatx4* az = (floatx4*)(agg + (size_t)n * 16);
    az[0] = z; az[1] = z;

    float ov[16];
    #pragma unroll
    for (int o = 0; o < 16; ++o) ov[o] = bias[o];
    #pragma unroll
    for (int i = 0; i < 16; ++i) {
        float hi = hv[i];
        #pragma unroll
        for (int o = 0; o < 16; ++o) ov[o] += hi * root[i * 16 + o];
    }
    float* orow = out + n * 16;
    #pragma unroll
    for (int i = 0; i < 4; ++i) ((floatx4*)orow)[i] = ((floatx4*)ov)[i];
}

// Kernel W: W2t[m][k] = bf16(W2[k][m]), [16][160] bf16 = 5 KB.
__global__ __launch_bounds__(256) void prep_kernel(
    const float* __restrict__ w_edge, const float* __restrict__ b_edge,
    short* __restrict__ w2t)
{
    int t = blockIdx.x * blockDim.x + threadIdx.x;
    if (t >= 16 * 160) return;
    int m = t / 160, k = t % 160;
    float v = 0.f;
    if (k < 128)      v = w_edge[(k >> 4) * 256 + (k & 15) * 16 + m];
    else if (k < 144) v = b_edge[(k - 128) * 16 + m];
    w2t[m * 160 + k] = f2bf(v);
}

// Kernel B: 4 tiles (64 edges) per wave. All independent loads (eidx, dst2,
// ea) issued up front; 4 independent h-gather chains; bfrag loaded once per
// wave. dst rows come from a direct 8B int2 load (replaces 4 bpermutes,
// address known at wave start). Epilogue: pk f16 atomics, 2 per lane per tile.
__global__ __launch_bounds__(256, 4) void edge_kernel(
    const int* __restrict__ eidx, const float* __restrict__ ea,
    const short* __restrict__ w2t, const float* __restrict__ h,
    __half* __restrict__ agg)
{
    const int lane = threadIdx.x & 63;
    const int wid  = threadIdx.x >> 6;
    const int m = lane & 15;   // edge-in-tile for A; output col for C/D and B
    const int q = lane >> 4;   // quad
    const int odd = m & 1;
    const int mlo = m & ~1;

    const int tile0 = (blockIdx.x * 4 + wid) * TPW;
    if (tile0 >= NTILES) return;

    // B fragments: shared across all tiles of this wave (w2t is tiny, L1-hot)
    const short* wp = w2t + m * 160 + 8 * q;
    short8 bfrag[5];
    #pragma unroll
    for (int c = 0; c < 5; ++c)
        bfrag[c] = *(const short8*)(wp + 32 * c);

    // Phase 1: issue all independent loads for all TPW tiles
    int src[TPW];
    int2 d2[TPW];
    floatx4 e0[TPW], e1[TPW];
    #pragma unroll
    for (int t = 0; t < TPW; ++t) {
        const int e = (tile0 + t) * 16 + m;
        src[t] = eidx[e];
        // this lane's two dst rows (4q+2*odd, +1): consecutive ints, 8B aligned
        d2[t] = *(const int2*)(eidx + E_EDGES + (tile0 + t) * 16 + 4 * q + 2 * odd);
        const float* er = ea + (size_t)e * 8;
        e0[t] = ((const floatx4*)er)[0];
        e1[t] = ((const floatx4*)er)[1];
    }

    // Phase 2: h gathers (each depends only on its own src)
    floatx4 g0[TPW], g1[TPW];
    #pragma unroll
    for (int t = 0; t < TPW; ++t) {
        const float* hr = h + src[t] * 16 + 8 * (q & 1);
        g0[t] = ((const floatx4*)hr)[0];
        g1[t] = ((const floatx4*)hr)[1];
    }

    // Phase 3: pack + MFMA + epilogue per tile (independent chains)
    const int hi_t = q >> 1;
    #pragma unroll
    for (int t = 0; t < TPW; ++t) {
        float hh[8] = {g0[t].x, g0[t].y, g0[t].z, g0[t].w,
                       g1[t].x, g1[t].y, g1[t].z, g1[t].w};
        floatx4 acc = {0.f, 0.f, 0.f, 0.f};
        #pragma unroll
        for (int c = 0; c < 4; ++c) {
            float te, to;
            if (c == 0)      { te = e0[t].x; to = e0[t].y; }
            else if (c == 1) { te = e0[t].z; to = e0[t].w; }
            else if (c == 2) { te = e1[t].x; to = e1[t].y; }
            else             { te = e1[t].z; to = e1[t].w; }
            float s = hi_t ? to : te;
            union { short8 s8; unsigned u[4]; } af;
            #pragma unroll
            for (int p = 0; p < 4; ++p)
                af.u[p] = pk_bf16(s * hh[2 * p], s * hh[2 * p + 1]);
            acc = __builtin_amdgcn_mfma_f32_16x16x32_bf16(af.s8, bfrag[c], acc, 0, 0, 0);
        }
        // chunk 4: z = h[i] for q<2, 0 otherwise (mask the packed words)
        {
            const unsigned msk = (q < 2) ? 0xFFFFFFFFu : 0u;
            union { short8 s8; unsigned u[4]; } af;
            #pragma unroll
            for (int p = 0; p < 4; ++p)
                af.u[p] = pk_bf16(hh[2 * p], hh[2 * p + 1]) & msk;
            acc = __builtin_amdgcn_mfma_f32_16x16x32_bf16(af.s8, bfrag[4], acc, 0, 0, 0);
        }

        // C/D layout: col = m, row = 4q + r. Pair adjacent cols via shfl_xor;
        // even lanes write rows 4q,4q+1; odd lanes rows 4q+2,4q+3.
        float px[4];
        #pragma unroll
        for (int r = 0; r < 4; ++r)
            px[r] = __shfl_xor(acc[r], 1, 64);
        #pragma unroll
        for (int k = 0; k < 2; ++k) {
            const int r = 2 * odd + k;
            float lo = odd ? px[r] : acc[r];
            float hi = odd ? acc[r] : px[r];
            __half2 v = __floats2half2_rn(lo, hi);
            const int dr = k ? d2[t].y : d2[t].x;
            unsafeAtomicAdd((__half2*)(agg + (size_t)dr * 16 + mlo), v);
        }
    }
}

// Kernel M: out += float(agg)
__global__ __launch_bounds__(256) void merge_kernel(
    const __half* __restrict__ agg, float* __restrict__ out)
{
    int n = blockIdx.x * blockDim.x + threadIdx.x;
    if (n >= N_NODES) return;
    const __half2* ar = (const __half2*)(agg + (size_t)n * 16);
    float* orow = out + (size_t)n * 16;
    floatx4 o[4];
    #pragma unroll
    for (int i = 0; i < 4; ++i) o[i] = ((floatx4*)orow)[i];
    #pragma unroll
    for (int j = 0; j < 8; ++j) {
        float2 f = __half22float2(ar[j]);
        o[j / 2][(j & 1) * 2 + 0] += f.x;
        o[j / 2][(j & 1) * 2 + 1] += f.y;
    }
    #pragma unroll
    for (int i = 0; i < 4; ++i) ((floatx4*)orow)[i] = o[i];
}

extern "C" void kernel_launch(void* const* d_in, const int* in_sizes, int n_in,
                              void* d_out, int out_size, void* d_ws, size_t ws_size,
                              hipStream_t stream) {
    const float* x        = (const float*)d_in[0];
    const int*   eidx     = (const int*)d_in[1];
    const float* ea       = (const float*)d_in[2];
    const float* ln_gamma = (const float*)d_in[3];
    const float* ln_beta  = (const float*)d_in[4];
    const float* w_edge   = (const float*)d_in[5];
    const float* b_edge   = (const float*)d_in[6];
    const float* root     = (const float*)d_in[7];
    const float* bias     = (const float*)d_in[8];
    float* out = (float*)d_out;

    // workspace: h [N*16 f32 = 3.2 MB] | w2t [16*160 bf16 = 5 KB] | agg [N*16 f16 = 1.6 MB]
    char* ws = (char*)d_ws;
    float*  h   = (float*)ws;
    short*  w2t = (short*)(ws + (size_t)N_NODES * 16 * 4);
    __half* agg = (__half*)(ws + (size_t)N_NODES * 16 * 4 + 16 * 160 * 2);

    prep_kernel<<<10, 256, 0, stream>>>(w_edge, b_edge, w2t);
    node_kernel<<<(N_NODES + 255) / 256, 256, 0, stream>>>(
        x, ln_gamma, ln_beta, root, bias, h, out, agg);
    // 4 tiles per wave: 12500 waves, 3125 blocks
    edge_kernel<<<(NTILES + 4 * TPW - 1) / (4 * TPW), 256, 0, stream>>>(
        eidx, ea, w2t, h, agg);
    merge_kernel<<<(N_NODES + 255) / 256, 256, 0, stream>>>(agg, out);
}

// Round 4
// 137.051 us; speedup vs baseline: 1.0642x; 1.0642x over previous
//
#include <hip/hip_runtime.h>
#include <hip/hip_fp16.h>

#define N_NODES 50000
#define E_EDGES 800000
#define NTILES  (E_EDGES / 16)   // 50000 exact
#define TPW 4                    // tiles per wave (ILP for latency hiding)

typedef __attribute__((ext_vector_type(8))) short short8;
typedef __attribute__((ext_vector_type(4))) float floatx4;

// float -> bf16 bits, round-to-nearest-even (used in prep only)
__device__ __forceinline__ short f2bf(float x) {
    union { float f; unsigned u; } v; v.f = x;
    unsigned r = v.u + 0x7FFFu + ((v.u >> 16) & 1u);
    return (short)(r >> 16);
}

// pack bf16x2 (RTZ) from two floats via v_perm_b32: 1 VALU per pair
__device__ __forceinline__ unsigned pk_bf16(float lo, float hi) {
    union { float f; unsigned u; } a, b; a.f = lo; b.f = hi;
    return __builtin_amdgcn_perm(b.u, a.u, 0x07060302u);
}

// Kernel A: per-node LayerNorm+ReLU -> h; out = bias + h @ root; zero agg row
__global__ __launch_bounds__(256) void node_kernel(
    const float* __restrict__ x, const float* __restrict__ gamma,
    const float* __restrict__ beta, const float* __restrict__ root,
    const float* __restrict__ bias, float* __restrict__ h,
    float* __restrict__ out, __half* __restrict__ agg)
{
    int n = blockIdx.x * blockDim.x + threadIdx.x;
    if (n >= N_NODES) return;
    const float* xr = x + n * 16;
    float xv[16];
    #pragma unroll
    for (int i = 0; i < 4; ++i) ((floatx4*)xv)[i] = ((const floatx4*)xr)[i];
    float mu = 0.f;
    #pragma unroll
    for (int i = 0; i < 16; ++i) mu += xv[i];
    mu *= (1.f / 16.f);
    float var = 0.f;
    #pragma unroll
    for (int i = 0; i < 16; ++i) { float d = xv[i] - mu; var += d * d; }
    var *= (1.f / 16.f);
    float rs = rsqrtf(var + 1e-5f);
    float hv[16];
    #pragma unroll
    for (int i = 0; i < 16; ++i) {
        float t = (xv[i] - mu) * rs * gamma[i] + beta[i];
        hv[i] = t > 0.f ? t : 0.f;
    }
    float* hr = h + n * 16;
    #pragma unroll
    for (int i = 0; i < 4; ++i) ((floatx4*)hr)[i] = ((floatx4*)hv)[i];

    // zero the f16 aggregation row for this node (32 B) before edge_kernel runs
    floatx4 z = {0.f, 0.f, 0.f, 0.f};
    floatx4* az = (floatx4*)(agg + (size_t)n * 16);
    az[0] = z; az[1] = z;

    float ov[16];
    #pragma unroll
    for (int o = 0; o < 16; ++o) ov[o] = bias[o];
    #pragma unroll
    for (int i = 0; i < 16; ++i) {
        float hi = hv[i];
        #pragma unroll
        for (int o = 0; o < 16; ++o) ov[o] += hi * root[i * 16 + o];
    }
    float* orow = out + n * 16;
    #pragma unroll
    for (int i = 0; i < 4; ++i) ((floatx4*)orow)[i] = ((floatx4*)ov)[i];
}

// Kernel W: W2t[m][k] = bf16(W2[k][m]), [16][160] bf16 = 5 KB.
__global__ __launch_bounds__(256) void prep_kernel(
    const float* __restrict__ w_edge, const float* __restrict__ b_edge,
    short* __restrict__ w2t)
{
    int t = blockIdx.x * blockDim.x + threadIdx.x;
    if (t >= 16 * 160) return;
    int m = t / 160, k = t % 160;
    float v = 0.f;
    if (k < 128)      v = w_edge[(k >> 4) * 256 + (k & 15) * 16 + m];
    else if (k < 144) v = b_edge[(k - 128) * 16 + m];
    w2t[m * 160 + k] = f2bf(v);
}

// Kernel B: 4 tiles (64 edges) per wave, with sched_barrier(0) fences pinning
// the phase structure (round-3 showed the compiler otherwise re-rolls it:
// VGPR_Count=36 proved loads were sunk to uses). Phase 1 issues ALL
// independent loads (eidx, dst2, ea) for 4 tiles; phase 2 issues all 8
// h-gathers; phase 3 computes per tile — s_waitcnt vmcnt(N) counting lets
// tile-0 compute overlap tiles-1..3 gathers. bfrag loaded once per wave.
__global__ __launch_bounds__(256, 4) void edge_kernel(
    const int* __restrict__ eidx, const float* __restrict__ ea,
    const short* __restrict__ w2t, const float* __restrict__ h,
    __half* __restrict__ agg)
{
    const int lane = threadIdx.x & 63;
    const int wid  = threadIdx.x >> 6;
    const int m = lane & 15;   // edge-in-tile for A; output col for C/D and B
    const int q = lane >> 4;   // quad
    const int odd = m & 1;
    const int mlo = m & ~1;

    const int tile0 = (blockIdx.x * 4 + wid) * TPW;
    if (tile0 >= NTILES) return;

    // B fragments: shared across all tiles of this wave (w2t is tiny, L1-hot)
    const short* wp = w2t + m * 160 + 8 * q;
    short8 bfrag[5];
    #pragma unroll
    for (int c = 0; c < 5; ++c)
        bfrag[c] = *(const short8*)(wp + 32 * c);

    // Phase 1: issue all independent loads for all TPW tiles
    int src[TPW];
    int2 d2[TPW];
    floatx4 e0[TPW], e1[TPW];
    #pragma unroll
    for (int t = 0; t < TPW; ++t) {
        const int e = (tile0 + t) * 16 + m;
        src[t] = eidx[e];
        // this lane's two dst rows (4q+2*odd, +1): consecutive ints, 8B aligned
        d2[t] = *(const int2*)(eidx + E_EDGES + (tile0 + t) * 16 + 4 * q + 2 * odd);
        const float* er = ea + (size_t)e * 8;
        e0[t] = ((const floatx4*)er)[0];
        e1[t] = ((const floatx4*)er)[1];
    }
    __builtin_amdgcn_sched_barrier(0);   // pin: all loads issued before anything below

    // Phase 2: h gathers (each depends only on its own src)
    floatx4 g0[TPW], g1[TPW];
    #pragma unroll
    for (int t = 0; t < TPW; ++t) {
        const float* hr = h + src[t] * 16 + 8 * (q & 1);
        g0[t] = ((const floatx4*)hr)[0];
        g1[t] = ((const floatx4*)hr)[1];
    }
    __builtin_amdgcn_sched_barrier(0);   // pin: all gathers issued before compute

    // Phase 3: pack + MFMA + epilogue per tile (independent chains)
    const int hi_t = q >> 1;
    #pragma unroll
    for (int t = 0; t < TPW; ++t) {
        float hh[8] = {g0[t].x, g0[t].y, g0[t].z, g0[t].w,
                       g1[t].x, g1[t].y, g1[t].z, g1[t].w};
        floatx4 acc = {0.f, 0.f, 0.f, 0.f};
        #pragma unroll
        for (int c = 0; c < 4; ++c) {
            float te, to;
            if (c == 0)      { te = e0[t].x; to = e0[t].y; }
            else if (c == 1) { te = e0[t].z; to = e0[t].w; }
            else if (c == 2) { te = e1[t].x; to = e1[t].y; }
            else             { te = e1[t].z; to = e1[t].w; }
            float s = hi_t ? to : te;
            union { short8 s8; unsigned u[4]; } af;
            #pragma unroll
            for (int p = 0; p < 4; ++p)
                af.u[p] = pk_bf16(s * hh[2 * p], s * hh[2 * p + 1]);
            acc = __builtin_amdgcn_mfma_f32_16x16x32_bf16(af.s8, bfrag[c], acc, 0, 0, 0);
        }
        // chunk 4: z = h[i] for q<2, 0 otherwise (mask the packed words)
        {
            const unsigned msk = (q < 2) ? 0xFFFFFFFFu : 0u;
            union { short8 s8; unsigned u[4]; } af;
            #pragma unroll
            for (int p = 0; p < 4; ++p)
                af.u[p] = pk_bf16(hh[2 * p], hh[2 * p + 1]) & msk;
            acc = __builtin_amdgcn_mfma_f32_16x16x32_bf16(af.s8, bfrag[4], acc, 0, 0, 0);
        }

        // C/D layout: col = m, row = 4q + r. Pair adjacent cols via shfl_xor;
        // even lanes write rows 4q,4q+1; odd lanes rows 4q+2,4q+3.
        float px[4];
        #pragma unroll
        for (int r = 0; r < 4; ++r)
            px[r] = __shfl_xor(acc[r], 1, 64);
        #pragma unroll
        for (int k = 0; k < 2; ++k) {
            const int r = 2 * odd + k;
            float lo = odd ? px[r] : acc[r];
            float hi = odd ? acc[r] : px[r];
            __half2 v = __floats2half2_rn(lo, hi);
            const int dr = k ? d2[t].y : d2[t].x;
            unsafeAtomicAdd((__half2*)(agg + (size_t)dr * 16 + mlo), v);
        }
    }
}

// Kernel M: out += float(agg)
__global__ __launch_bounds__(256) void merge_kernel(
    const __half* __restrict__ agg, float* __restrict__ out)
{
    int n = blockIdx.x * blockDim.x + threadIdx.x;
    if (n >= N_NODES) return;
    const __half2* ar = (const __half2*)(agg + (size_t)n * 16);
    float* orow = out + (size_t)n * 16;
    floatx4 o[4];
    #pragma unroll
    for (int i = 0; i < 4; ++i) o[i] = ((floatx4*)orow)[i];
    #pragma unroll
    for (int j = 0; j < 8; ++j) {
        float2 f = __half22float2(ar[j]);
        o[j / 2][(j & 1) * 2 + 0] += f.x;
        o[j / 2][(j & 1) * 2 + 1] += f.y;
    }
    #pragma unroll
    for (int i = 0; i < 4; ++i) ((floatx4*)orow)[i] = o[i];
}

extern "C" void kernel_launch(void* const* d_in, const int* in_sizes, int n_in,
                              void* d_out, int out_size, void* d_ws, size_t ws_size,
                              hipStream_t stream) {
    const float* x        = (const float*)d_in[0];
    const int*   eidx     = (const int*)d_in[1];
    const float* ea       = (const float*)d_in[2];
    const float* ln_gamma = (const float*)d_in[3];
    const float* ln_beta  = (const float*)d_in[4];
    const float* w_edge   = (const float*)d_in[5];
    const float* b_edge   = (const float*)d_in[6];
    const float* root     = (const float*)d_in[7];
    const float* bias     = (const float*)d_in[8];
    float* out = (float*)d_out;

    // workspace: h [N*16 f32 = 3.2 MB] | w2t [16*160 bf16 = 5 KB] | agg [N*16 f16 = 1.6 MB]
    char* ws = (char*)d_ws;
    float*  h   = (float*)ws;
    short*  w2t = (short*)(ws + (size_t)N_NODES * 16 * 4);
    __half* agg = (__half*)(ws + (size_t)N_NODES * 16 * 4 + 16 * 160 * 2);

    prep_kernel<<<10, 256, 0, stream>>>(w_edge, b_edge, w2t);
    node_kernel<<<(N_NODES + 255) / 256, 256, 0, stream>>>(
        x, ln_gamma, ln_beta, root, bias, h, out, agg);
    // 4 tiles per wave: 12500 waves, 3125 blocks
    edge_kernel<<<(NTILES + 4 * TPW - 1) / (4 * TPW), 256, 0, stream>>>(
        eidx, ea, w2t, h, agg);
    merge_kernel<<<(N_NODES + 255) / 256, 256, 0, stream>>>(agg, out);
}